// Round 1
// baseline (1142.807 us; speedup 1.0000x reference)
//
#include <hip/hip_runtime.h>
#include <hip/hip_bf16.h>

// Problem constants (from setup_inputs): M=8 ensemble, B=4096 batch, I=2048 in, O=2048 out
#define M_ENS 8
#define BB    4096
#define KK    2048   // I (contraction dim)
#define OO    2048   // O

typedef __bf16 bf16x8 __attribute__((ext_vector_type(8)));
typedef float  f32x4  __attribute__((ext_vector_type(4)));

__device__ __forceinline__ unsigned short f2bf(float f) {
    __hip_bfloat16 h = __float2bfloat16(f);   // RNE
    return __builtin_bit_cast(unsigned short, h);
}

__device__ __forceinline__ float softplus_f(float x) {
    // numerically stable softplus: max(x,0) + log1p(exp(-|x|))
    return fmaxf(x, 0.f) + log1pf(__expf(-fabsf(x)));
}

// async global->LDS, 16B per lane, LDS dest = wave-uniform base + lane*16
typedef __attribute__((address_space(1))) unsigned int gu32;
typedef __attribute__((address_space(3))) unsigned int su32;
__device__ __forceinline__ void gload_lds16(const void* g, void* s) {
    __builtin_amdgcn_global_load_lds((gu32*)g, (su32*)s, 16, 0, 0);
}

// ---------------------------------------------------------------------------
// Kernel 1: wT[m][o][i] = bf16( mu[m][i][o] + softplus(rho[m][i][o])*eps[m][i][o] )
//
// v2: LDS tile transpose. The old version stored 16B per lane at 4KB stride
// (one cacheline per lane -> partial-line RMW traffic, ~550 us). Now a 64x64
// (o x i) tile goes through LDS so BOTH global sides are coalesced:
//   phase 1: reads contiguous along o (256B per wave per row), bf16 pack,
//            2x ds_write_b128 per thread (row stride 72 elems = 9 x 16B units,
//            odd -> conflict-free).
//   phase 2: 8 lanes cover one o-row's 64 i (128B contiguous global store,
//            full cachelines, no RMW). LDS read units o*9+c distinct mod 8
//            -> conflict-free.
// ---------------------------------------------------------------------------
#define TI  64
#define TO  64
#define LDT 72   // sT row stride in bf16 elements

__global__ __launch_bounds__(256) void prep_w(const float* __restrict__ mu,
                                              const float* __restrict__ rho,
                                              const float* __restrict__ eps,
                                              unsigned short* __restrict__ wT) {
    __shared__ __align__(16) unsigned short sT[TO * LDT];   // 9216 B, [o][i]

    const int o0 = blockIdx.x * TO;
    const int i0 = blockIdx.y * TI;
    const int m  = blockIdx.z;
    const size_t base_in  = (size_t)m * KK * OO;   // [i][o]
    const size_t base_out = (size_t)m * OO * KK;   // [o][i]

    const int tid    = threadIdx.x;
    const int o_l    = tid & 63;          // one wave = one o-row segment
    const int i_base = (tid >> 6) * 16;   // wave w covers i_base = 16w .. +15

    union { unsigned short us[16]; uint4 q[2]; } pk;
#pragma unroll
    for (int j = 0; j < 16; ++j) {
        const size_t idx = base_in + (size_t)(i0 + i_base + j) * OO + (o0 + o_l);
        pk.us[j] = f2bf(fmaf(softplus_f(rho[idx]), eps[idx], mu[idx]));
    }
    *reinterpret_cast<uint4*>(&sT[o_l * LDT + i_base])     = pk.q[0];
    *reinterpret_cast<uint4*>(&sT[o_l * LDT + i_base + 8]) = pk.q[1];

    __syncthreads();

    // write-out: lane group of 8 covers one o-row (64 i = 128B contiguous)
#pragma unroll
    for (int p = 0; p < 2; ++p) {
        const int o_w = p * 32 + (tid >> 3);
        const int i_c = (tid & 7) * 8;
        *reinterpret_cast<uint4*>(&wT[base_out + (size_t)(o0 + o_w) * KK + i0 + i_c]) =
            *reinterpret_cast<const uint4*>(&sT[o_w * LDT + i_c]);
    }
}

// ---------------------------------------------------------------------------
// Kernel 2: out[m] = x[m] (fp32 4096x2048) @ w[m] (bf16, stored transposed
//           [O][K]) + bias[m], 128x128 tile, BK=32, 16x16x32 bf16 MFMA.
//           (unchanged this round — control for the prep_w fix)
// ---------------------------------------------------------------------------
#define BM  128
#define BN  128
#define BKT 32
#define LDA 40   // sA row stride in bf16 elements (+8 pad -> conflict-free b128)

__global__ __launch_bounds__(256) void gemm_kernel(const float* __restrict__ x,
                                                   const unsigned short* __restrict__ wT,
                                                   const float* __restrict__ bmu,
                                                   const float* __restrict__ brho,
                                                   const float* __restrict__ beps,
                                                   float* __restrict__ out) {
    // sB MUST be unpadded [BN][BKT] (global_load_lds order); XOR swizzle breaks conflicts
    __shared__ __align__(16) unsigned short sB[BN * BKT];   // 8 KB
    __shared__ __align__(16) unsigned short sA[BM * LDA];   // 10 KB
    __shared__ float sBias[BN];

    const int tid = threadIdx.x;
    const int w   = tid >> 6;      // wave 0..3
    const int l   = tid & 63;      // lane
    const int lr  = l & 15;        // MFMA row/col within frag
    const int lq  = l >> 4;        // MFMA quad
    const int n0   = blockIdx.x * BN;
    const int row0 = blockIdx.y * BM;
    const int m    = blockIdx.z;

    const float*          xm  = x   + (size_t)m * BB * KK;
    const unsigned short* wTm = wT  + (size_t)m * OO * KK;
    float*                om  = out + (size_t)m * BB * OO;

    // fused bias: b[o] = bmu + softplus(brho)*beps, for this block's 128 cols
    if (tid < BN) {
        const size_t bi = (size_t)m * OO + n0 + tid;
        sBias[tid] = fmaf(softplus_f(brho[bi]), beps[bi], bmu[bi]);
    }

    const int wm = w >> 1, wn = w & 1;   // wave tile: 64x64

    f32x4 acc[4][4];
#pragma unroll
    for (int a = 0; a < 4; ++a)
#pragma unroll
        for (int b = 0; b < 4; ++b)
#pragma unroll
            for (int j = 0; j < 4; ++j) acc[a][b][j] = 0.f;

    // --- B staging addresses (global_load_lds, 2 instrs/wave) ---
    // instr covers 16 rows (64B each); lane l -> row 16w + (l>>2), chunk l&3.
    // LDS slot (r,c) holds global chunk c ^ ((r>>1)&3)  [self-inverse swizzle]
    const int bswz = ((l & 3) ^ ((l >> 3) & 3)) * 8;   // global k-chunk offset (elems)
    const unsigned short* gB0 = wTm + (size_t)(n0 + 16 * w + (l >> 2)) * KK + bswz;
    const unsigned short* gB1 = gB0 + (size_t)64 * KK;
    unsigned short* sBw0 = sB + w * 512;          // bytes w*1024 (wave-uniform)
    unsigned short* sBw1 = sB + 2048 + w * 512;   // bytes 4096 + w*1024

    // --- A staging addresses (fp32 load -> bf16 -> ds_write) ---
    const int arow = tid >> 1, ahalf = tid & 1;   // row 0..127, 16-float half
    const float* gA = xm + (size_t)(row0 + arow) * KK + ahalf * 16;
    unsigned short* sAw = sA + arow * LDA + ahalf * 16;

    const int bq = (lq ^ ((lr >> 1) & 3)) * 8;    // read-side swizzled k-chunk (elems)

    for (int kt = 0; kt < KK / BKT; ++kt) {
        const int k0 = kt * BKT;

        // B tile: w^T rows [n0..n0+127], k chunk -> LDS (async DMA)
        gload_lds16(gB0 + k0, sBw0);
        gload_lds16(gB1 + k0, sBw1);

        // A tile: 16 fp32 per thread -> 16 bf16 -> 2x ds_write_b128
        const float4 f0 = *reinterpret_cast<const float4*>(gA + k0);
        const float4 f1 = *reinterpret_cast<const float4*>(gA + k0 + 4);
        const float4 f2 = *reinterpret_cast<const float4*>(gA + k0 + 8);
        const float4 f3 = *reinterpret_cast<const float4*>(gA + k0 + 12);
        union { unsigned short us[16]; uint4 q[2]; } pk;
        pk.us[0]  = f2bf(f0.x); pk.us[1]  = f2bf(f0.y); pk.us[2]  = f2bf(f0.z); pk.us[3]  = f2bf(f0.w);
        pk.us[4]  = f2bf(f1.x); pk.us[5]  = f2bf(f1.y); pk.us[6]  = f2bf(f1.z); pk.us[7]  = f2bf(f1.w);
        pk.us[8]  = f2bf(f2.x); pk.us[9]  = f2bf(f2.y); pk.us[10] = f2bf(f2.z); pk.us[11] = f2bf(f2.w);
        pk.us[12] = f2bf(f3.x); pk.us[13] = f2bf(f3.y); pk.us[14] = f2bf(f3.z); pk.us[15] = f2bf(f3.w);
        *reinterpret_cast<uint4*>(sAw)     = pk.q[0];
        *reinterpret_cast<uint4*>(sAw + 8) = pk.q[1];

        __syncthreads();   // drains vmcnt (global_load_lds) + lgkm

        bf16x8 af[4], bv[4];
#pragma unroll
        for (int a = 0; a < 4; ++a)
            af[a] = *reinterpret_cast<const bf16x8*>(&sA[(wm * 64 + a * 16 + lr) * LDA + lq * 8]);
#pragma unroll
        for (int b = 0; b < 4; ++b)
            bv[b] = *reinterpret_cast<const bf16x8*>(&sB[(wn * 64 + b * 16 + lr) * BKT + bq]);

#pragma unroll
        for (int a = 0; a < 4; ++a)
#pragma unroll
            for (int b = 0; b < 4; ++b)
                acc[a][b] = __builtin_amdgcn_mfma_f32_16x16x32_bf16(af[a], bv[b], acc[a][b], 0, 0, 0);

        __syncthreads();   // before next iteration overwrites LDS
    }

    // epilogue: C/D layout col = lane&15, row = quad*4 + reg
#pragma unroll
    for (int b = 0; b < 4; ++b) {
        const int col  = wn * 64 + b * 16 + lr;
        const float bias = sBias[col];
#pragma unroll
        for (int a = 0; a < 4; ++a) {
            const int rbase = row0 + wm * 64 + a * 16 + lq * 4;
            float* po = om + (size_t)rbase * OO + n0 + col;
#pragma unroll
            for (int j = 0; j < 4; ++j)
                po[(size_t)j * OO] = acc[a][b][j] + bias;
        }
    }
}

extern "C" void kernel_launch(void* const* d_in, const int* in_sizes, int n_in,
                              void* d_out, int out_size, void* d_ws, size_t ws_size,
                              hipStream_t stream) {
    const float* x    = (const float*)d_in[0];
    const float* wmu  = (const float*)d_in[1];
    const float* wrho = (const float*)d_in[2];
    const float* bmu  = (const float*)d_in[3];
    const float* brho = (const float*)d_in[4];
    const float* ew   = (const float*)d_in[5];
    const float* eb   = (const float*)d_in[6];
    float* out = (float*)d_out;

    unsigned short* wT = (unsigned short*)d_ws;  // 8*2048*2048*2 = 64 MiB

    prep_w<<<dim3(OO / TO, KK / TI, M_ENS), 256, 0, stream>>>(wmu, wrho, ew, wT);
    gemm_kernel<<<dim3(OO / BN, BB / BM, M_ENS), 256, 0, stream>>>(x, wT, bmu, brho, eb, out);
}

// Round 2
// 938.256 us; speedup vs baseline: 1.2180x; 1.2180x over previous
//
#include <hip/hip_runtime.h>
#include <hip/hip_bf16.h>

// Problem constants: M=8 ensemble, B=4096 batch, I=2048 in, O=2048 out
#define M_ENS 8
#define BB    4096
#define KK    2048   // I (contraction dim)
#define OO    2048   // O

typedef __bf16 bf16x8 __attribute__((ext_vector_type(8)));
typedef float  f32x4  __attribute__((ext_vector_type(4)));

__device__ __forceinline__ unsigned short f2bf(float f) {
    __hip_bfloat16 h = __float2bfloat16(f);   // RNE
    return __builtin_bit_cast(unsigned short, h);
}

__device__ __forceinline__ float softplus_f(float x) {
    return fmaxf(x, 0.f) + log1pf(__expf(-fabsf(x)));
}

// async global->LDS, 16B per lane, LDS dest = wave-uniform base + lane*16
typedef __attribute__((address_space(1))) unsigned int gu32;
typedef __attribute__((address_space(3))) unsigned int su32;
__device__ __forceinline__ void gload_lds16(const void* g, void* s) {
    __builtin_amdgcn_global_load_lds((gu32*)g, (su32*)s, 16, 0, 0);
}

// ---------------------------------------------------------------------------
// Kernel 1: wT[m][o][i] = bf16(mu + softplus(rho)*eps), via 64x64 LDS transpose
// ---------------------------------------------------------------------------
#define TI  64
#define TO  64
#define LDT 72

__global__ __launch_bounds__(256) void prep_w(const float* __restrict__ mu,
                                              const float* __restrict__ rho,
                                              const float* __restrict__ eps,
                                              unsigned short* __restrict__ wT) {
    __shared__ __align__(16) unsigned short sT[TO * LDT];

    const int o0 = blockIdx.x * TO;
    const int i0 = blockIdx.y * TI;
    const int m  = blockIdx.z;
    const size_t base_in  = (size_t)m * KK * OO;   // [i][o]
    const size_t base_out = (size_t)m * OO * KK;   // [o][i]

    const int tid    = threadIdx.x;
    const int o_l    = tid & 63;
    const int i_base = (tid >> 6) * 16;

    union { unsigned short us[16]; uint4 q[2]; } pk;
#pragma unroll
    for (int j = 0; j < 16; ++j) {
        const size_t idx = base_in + (size_t)(i0 + i_base + j) * OO + (o0 + o_l);
        pk.us[j] = f2bf(fmaf(softplus_f(rho[idx]), eps[idx], mu[idx]));
    }
    *reinterpret_cast<uint4*>(&sT[o_l * LDT + i_base])     = pk.q[0];
    *reinterpret_cast<uint4*>(&sT[o_l * LDT + i_base + 8]) = pk.q[1];

    __syncthreads();

#pragma unroll
    for (int p = 0; p < 2; ++p) {
        const int o_w = p * 32 + (tid >> 3);
        const int i_c = (tid & 7) * 8;
        *reinterpret_cast<uint4*>(&wT[base_out + (size_t)(o0 + o_w) * KK + i0 + i_c]) =
            *reinterpret_cast<const uint4*>(&sT[o_w * LDT + i_c]);
    }
}

// ---------------------------------------------------------------------------
// Kernel 1b: xb = bf16(x), flat elementwise (fp32 x is read once by GEMM as bf16)
// ---------------------------------------------------------------------------
__global__ __launch_bounds__(256) void prep_x(const float* __restrict__ x,
                                              unsigned short* __restrict__ xb) {
    const size_t i = ((size_t)blockIdx.x * 256 + threadIdx.x) * 8;
    const float4 f0 = *reinterpret_cast<const float4*>(x + i);
    const float4 f1 = *reinterpret_cast<const float4*>(x + i + 4);
    union { unsigned short us[8]; uint4 q; } pk;
    pk.us[0] = f2bf(f0.x); pk.us[1] = f2bf(f0.y); pk.us[2] = f2bf(f0.z); pk.us[3] = f2bf(f0.w);
    pk.us[4] = f2bf(f1.x); pk.us[5] = f2bf(f1.y); pk.us[6] = f2bf(f1.z); pk.us[7] = f2bf(f1.w);
    *reinterpret_cast<uint4*>(xb + i) = pk.q;
}

// ---------------------------------------------------------------------------
// Kernel 2 (new): 256x256 tile, BK=64, 8 waves (2Mx4N), 8-phase schedule with
// counted vmcnt, XOR chunk swizzle (pre-swizzled global src + swizzled ds_read),
// s_setprio around MFMA clusters. Double-buffered 128 KiB LDS.
// ---------------------------------------------------------------------------
#define NKT (KK / 64)   // 32 K-tiles

#define BAR()   asm volatile("s_barrier" ::: "memory")
#define LGKM0() asm volatile("s_waitcnt lgkmcnt(0)" ::: "memory")
#define SCHB()  __builtin_amdgcn_sched_barrier(0)
#define PRIO1() __builtin_amdgcn_s_setprio(1)
#define PRIO0() __builtin_amdgcn_s_setprio(0)

// LDS elem (ushort) layout: buf p: A @ p*32768, B @ p*32768+16384 ; row=64 elems
#define RD_A(P, HALF, mf, ks) \
    (*reinterpret_cast<const bf16x8*>(sLds + (P)*32768 + aoff + (HALF)*4096 + (mf)*1024 + ((ks) ? ck1 : ck0)))
#define RD_B(P, nf, ks) \
    (*reinterpret_cast<const bf16x8*>(sLds + (P)*32768 + boff + (nf)*1024 + ((ks) ? ck1 : ck0)))

#define ISSUE_A(P, T, J) gload_lds16(gAl + (size_t)(T)*64 + (size_t)(J)*(64*KK), \
                                     sLds + (P)*32768 + (J)*4096 + wofs)
#define ISSUE_B(P, T, J) gload_lds16(gBl + (size_t)(T)*64 + (size_t)(J)*(64*KK), \
                                     sLds + (P)*32768 + 16384 + (J)*4096 + wofs)

#define MFMA_Q(MH, NH) \
    _Pragma("unroll") \
    for (int ks_ = 0; ks_ < 2; ++ks_) \
        _Pragma("unroll") \
        for (int mf_ = 0; mf_ < 4; ++mf_) \
            _Pragma("unroll") \
            for (int nf_ = 0; nf_ < 2; ++nf_) \
                acc[(MH)*4 + mf_][(NH)*2 + nf_] = __builtin_amdgcn_mfma_f32_16x16x32_bf16( \
                    af[mf_][ks_], bv[(NH)*2 + nf_][ks_], acc[(MH)*4 + mf_][(NH)*2 + nf_], 0, 0, 0);

// one K-tile = 4 phases; stages: P1/P2 -> A(t+1) into buf P^1, P3/P4 -> B(t+2) into buf P
#define TILE(T, P) do { \
    _Pragma("unroll") for (int m_ = 0; m_ < 4; ++m_) { \
        af[m_][0] = RD_A(P, 0, m_, 0); af[m_][1] = RD_A(P, 0, m_, 1); } \
    _Pragma("unroll") for (int n_ = 0; n_ < 2; ++n_) { \
        bv[n_][0] = RD_B(P, n_, 0); bv[n_][1] = RD_B(P, n_, 1); } \
    if ((T) + 1 < NKT) { ISSUE_A((P)^1, (T)+1, 0); ISSUE_A((P)^1, (T)+1, 1); } \
    BAR(); LGKM0(); SCHB(); PRIO1(); MFMA_Q(0, 0); PRIO0(); BAR(); \
    _Pragma("unroll") for (int n_ = 0; n_ < 2; ++n_) { \
        bv[2+n_][0] = RD_B(P, 2+n_, 0); bv[2+n_][1] = RD_B(P, 2+n_, 1); } \
    if ((T) + 1 < NKT) { ISSUE_A((P)^1, (T)+1, 2); ISSUE_A((P)^1, (T)+1, 3); } \
    BAR(); LGKM0(); SCHB(); PRIO1(); MFMA_Q(0, 1); PRIO0(); BAR(); \
    _Pragma("unroll") for (int m_ = 0; m_ < 4; ++m_) { \
        af[m_][0] = RD_A(P, 1, m_, 0); af[m_][1] = RD_A(P, 1, m_, 1); } \
    if ((T) + 2 < NKT) { ISSUE_B(P, (T)+2, 0); ISSUE_B(P, (T)+2, 1); } \
    BAR(); LGKM0(); SCHB(); PRIO1(); MFMA_Q(1, 0); PRIO0(); BAR(); \
    if ((T) + 2 < NKT) { ISSUE_B(P, (T)+2, 2); ISSUE_B(P, (T)+2, 3); \
                         asm volatile("s_waitcnt vmcnt(4)" ::: "memory"); } \
    else               { asm volatile("s_waitcnt vmcnt(0)" ::: "memory"); } \
    BAR(); SCHB(); PRIO1(); MFMA_Q(1, 1); PRIO0(); BAR(); \
} while (0)

__global__ __launch_bounds__(512, 2) void gemm8(const unsigned short* __restrict__ xb,
                                                const unsigned short* __restrict__ wT,
                                                const float* __restrict__ bmu,
                                                const float* __restrict__ brho,
                                                const float* __restrict__ beps,
                                                float* __restrict__ out) {
    __shared__ __align__(16) unsigned short sLds[65536];   // 128 KiB: 2 x (A 32K + B 32K)

    const int tid = threadIdx.x;
    const int w   = tid >> 6;      // 0..7
    const int l   = tid & 63;
    const int lr  = l & 15;
    const int lq  = l >> 4;
    const int wm  = w >> 2;        // 0..1 : row half (128 rows)
    const int wn  = w & 3;         // 0..3 : col quarter (64 cols)
    const int m   = blockIdx.y;

    // XCD-aware bijective swizzle within the 128-block m-plane (128 % 8 == 0)
    const int b    = blockIdx.x;
    const int swz  = (b & 7) * 16 + (b >> 3);
    const int n0   = (swz & 7) * 256;    // O tiles: 8
    const int row0 = (swz >> 3) * 256;   // B tiles: 16

    const unsigned short* xbm = xb + (size_t)m * BB * KK;
    const unsigned short* wTm = wT + (size_t)m * OO * KK;

    // staging per-lane constants: row srow = w*8 + (l>>3); global chunk pre-swizzle
    const int srow = w * 8 + (l >> 3);
    const int sgc  = (l & 7) ^ (l >> 3);
    const unsigned short* gAl = xbm + (size_t)(row0 + srow) * KK + sgc * 8;
    const unsigned short* gBl = wTm + (size_t)(n0 + srow) * KK + sgc * 8;
    const int wofs = w * 512;   // elems: wave-uniform LDS base inside a 64-row issue

    // read-side swizzled chunk offsets: cc' = (ks*4+lq) ^ (lr&7)
    const int h   = lr & 7;
    const int u   = lq ^ (h & 3);
    const int ck0 = (((h & 4)) | u) * 8;
    const int ck1 = ((4 ^ (h & 4)) | u) * 8;
    const int aoff = (wm * 128 + lr) * 64;
    const int boff = 16384 + (wn * 64 + lr) * 64;

    f32x4 acc[8][4];
#pragma unroll
    for (int a = 0; a < 8; ++a)
#pragma unroll
        for (int c = 0; c < 4; ++c)
#pragma unroll
            for (int j = 0; j < 4; ++j) acc[a][c][j] = 0.f;

    bf16x8 af[4][2], bv[4][2];

    // prologue: tile0 A+B -> buf0, tile1 B -> buf1  (12 issues; keep last 4 in flight)
    ISSUE_A(0, 0, 0); ISSUE_A(0, 0, 1); ISSUE_A(0, 0, 2); ISSUE_A(0, 0, 3);
    ISSUE_B(0, 0, 0); ISSUE_B(0, 0, 1); ISSUE_B(0, 0, 2); ISSUE_B(0, 0, 3);
    ISSUE_B(1, 1, 0); ISSUE_B(1, 1, 1); ISSUE_B(1, 1, 2); ISSUE_B(1, 1, 3);
    asm volatile("s_waitcnt vmcnt(4)" ::: "memory");
    BAR();

    for (int t2 = 0; t2 < NKT; t2 += 2) {
        TILE(t2, 0);
        TILE(t2 + 1, 1);
    }

    // epilogue: D row = lq*4 + j, col = lr ; bias fused from bmu/brho/beps
    const size_t obase = (size_t)m * BB * OO;
#pragma unroll
    for (int nf = 0; nf < 4; ++nf) {
        const int col = n0 + wn * 64 + nf * 16 + lr;
        const size_t bi = (size_t)m * OO + col;
        const float bias = fmaf(softplus_f(brho[bi]), beps[bi], bmu[bi]);
#pragma unroll
        for (int mf = 0; mf < 8; ++mf) {
            float* po = out + obase + (size_t)(row0 + wm * 128 + mf * 16 + lq * 4) * OO + col;
#pragma unroll
            for (int j = 0; j < 4; ++j)
                po[(size_t)j * OO] = acc[mf][nf][j] + bias;
        }
    }
}

// ---------------------------------------------------------------------------
// Fallback GEMM (verified 128x128 kernel) for small workspace
// ---------------------------------------------------------------------------
#define BM  128
#define BN  128
#define BKT 32
#define LDA 40

__global__ __launch_bounds__(256) void gemm_kernel(const float* __restrict__ x,
                                                   const unsigned short* __restrict__ wT,
                                                   const float* __restrict__ bmu,
                                                   const float* __restrict__ brho,
                                                   const float* __restrict__ beps,
                                                   float* __restrict__ out) {
    __shared__ __align__(16) unsigned short sB[BN * BKT];
    __shared__ __align__(16) unsigned short sA[BM * LDA];
    __shared__ float sBias[BN];

    const int tid = threadIdx.x;
    const int w   = tid >> 6;
    const int l   = tid & 63;
    const int lr  = l & 15;
    const int lq  = l >> 4;
    const int n0   = blockIdx.x * BN;
    const int row0 = blockIdx.y * BM;
    const int m    = blockIdx.z;

    const float*          xm  = x   + (size_t)m * BB * KK;
    const unsigned short* wTm = wT  + (size_t)m * OO * KK;
    float*                om  = out + (size_t)m * BB * OO;

    if (tid < BN) {
        const size_t bi = (size_t)m * OO + n0 + tid;
        sBias[tid] = fmaf(softplus_f(brho[bi]), beps[bi], bmu[bi]);
    }

    const int wm = w >> 1, wn = w & 1;

    f32x4 acc[4][4];
#pragma unroll
    for (int a = 0; a < 4; ++a)
#pragma unroll
        for (int c = 0; c < 4; ++c)
#pragma unroll
            for (int j = 0; j < 4; ++j) acc[a][c][j] = 0.f;

    const int bswz = ((l & 3) ^ ((l >> 3) & 3)) * 8;
    const unsigned short* gB0 = wTm + (size_t)(n0 + 16 * w + (l >> 2)) * KK + bswz;
    const unsigned short* gB1 = gB0 + (size_t)64 * KK;
    unsigned short* sBw0 = sB + w * 512;
    unsigned short* sBw1 = sB + 2048 + w * 512;

    const int arow = tid >> 1, ahalf = tid & 1;
    const float* gA = xm + (size_t)(row0 + arow) * KK + ahalf * 16;
    unsigned short* sAw = sA + arow * LDA + ahalf * 16;

    const int bq = (lq ^ ((lr >> 1) & 3)) * 8;

    for (int kt = 0; kt < KK / BKT; ++kt) {
        const int k0 = kt * BKT;
        gload_lds16(gB0 + k0, sBw0);
        gload_lds16(gB1 + k0, sBw1);

        const float4 f0 = *reinterpret_cast<const float4*>(gA + k0);
        const float4 f1 = *reinterpret_cast<const float4*>(gA + k0 + 4);
        const float4 f2 = *reinterpret_cast<const float4*>(gA + k0 + 8);
        const float4 f3 = *reinterpret_cast<const float4*>(gA + k0 + 12);
        union { unsigned short us[16]; uint4 q[2]; } pk;
        pk.us[0]  = f2bf(f0.x); pk.us[1]  = f2bf(f0.y); pk.us[2]  = f2bf(f0.z); pk.us[3]  = f2bf(f0.w);
        pk.us[4]  = f2bf(f1.x); pk.us[5]  = f2bf(f1.y); pk.us[6]  = f2bf(f1.z); pk.us[7]  = f2bf(f1.w);
        pk.us[8]  = f2bf(f2.x); pk.us[9]  = f2bf(f2.y); pk.us[10] = f2bf(f2.z); pk.us[11] = f2bf(f2.w);
        pk.us[12] = f2bf(f3.x); pk.us[13] = f2bf(f3.y); pk.us[14] = f2bf(f3.z); pk.us[15] = f2bf(f3.w);
        *reinterpret_cast<uint4*>(sAw)     = pk.q[0];
        *reinterpret_cast<uint4*>(sAw + 8) = pk.q[1];

        __syncthreads();

        bf16x8 afv[4], bvv[4];
#pragma unroll
        for (int a = 0; a < 4; ++a)
            afv[a] = *reinterpret_cast<const bf16x8*>(&sA[(wm * 64 + a * 16 + lr) * LDA + lq * 8]);
#pragma unroll
        for (int c = 0; c < 4; ++c)
            bvv[c] = *reinterpret_cast<const bf16x8*>(&sB[(wn * 64 + c * 16 + lr) * BKT + bq]);

#pragma unroll
        for (int a = 0; a < 4; ++a)
#pragma unroll
            for (int c = 0; c < 4; ++c)
                acc[a][c] = __builtin_amdgcn_mfma_f32_16x16x32_bf16(afv[a], bvv[c], acc[a][c], 0, 0, 0);

        __syncthreads();
    }

#pragma unroll
    for (int c = 0; c < 4; ++c) {
        const int col  = wn * 64 + c * 16 + lr;
        const float bias = sBias[col];
#pragma unroll
        for (int a = 0; a < 4; ++a) {
            const int rbase = row0 + wm * 64 + a * 16 + lq * 4;
            float* po = om + (size_t)rbase * OO + n0 + col;
#pragma unroll
            for (int j = 0; j < 4; ++j)
                po[(size_t)j * OO] = acc[a][c][j] + bias;
        }
    }
}

extern "C" void kernel_launch(void* const* d_in, const int* in_sizes, int n_in,
                              void* d_out, int out_size, void* d_ws, size_t ws_size,
                              hipStream_t stream) {
    const float* x    = (const float*)d_in[0];
    const float* wmu  = (const float*)d_in[1];
    const float* wrho = (const float*)d_in[2];
    const float* bmu  = (const float*)d_in[3];
    const float* brho = (const float*)d_in[4];
    const float* ew   = (const float*)d_in[5];
    const float* eb   = (const float*)d_in[6];
    float* out = (float*)d_out;

    const size_t needW = (size_t)M_ENS * OO * KK;   // ushort elems (64 MiB)
    const size_t needX = (size_t)M_ENS * BB * KK;   // ushort elems (128 MiB)

    unsigned short* wT = (unsigned short*)d_ws;

    prep_w<<<dim3(OO / TO, KK / TI, M_ENS), 256, 0, stream>>>(wmu, wrho, ew, wT);

    if (ws_size >= (needW + needX) * sizeof(unsigned short)) {
        unsigned short* xbuf = wT + needW;
        prep_x<<<dim3((unsigned)(needX / 8 / 256)), 256, 0, stream>>>(x, xbuf);
        gemm8<<<dim3((OO / 256) * (BB / 256), M_ENS), 512, 0, stream>>>(xbuf, wT, bmu, brho, eb, out);
    } else {
        gemm_kernel<<<dim3(OO / BN, BB / BM, M_ENS), 256, 0, stream>>>(x, wT, bmu, brho, eb, out);
    }
}